// Round 8
// baseline (172.255 us; speedup 1.0000x reference)
//
#include <hip/hip_runtime.h>
#include <cstdint>
#include <cstddef>

// ---------------------------------------------------------------------------
// LSTM cell, B=8192, D=H=512, fp32 in/out.
// pre = [x|h] @ Wstack^T + bias ; gates -> c_t, h_t fused in GEMM epilogue.
// Round 11: counted-vmcnt pipeline on the champion structure at PRESERVED
// occupancy. BK=32, THREE buffers (3 x 24576 = 72KB -> still 2 blk/CU),
// prefetch distance 2, raw s_barrier + s_waitcnt vmcnt(3) so the newest
// stage stays in flight ACROSS the barrier (r10 showed __syncthreads'
// vmcnt(0) drain kills same-step prefetch; this is the only structure that
// keeps loads airborne while retaining the simple single-phase loop that
// beat all complex schedules in r4-r8).
// Hazards: stage(kt+2) writes buf (kt+2)%3 whose last readers (step kt-1)
// finished pre-barrier (reads consumed by MFMA lgkmcnt); step kt's reads
// need stage(kt) which every wave confirmed via vmcnt(3) before the
// end-of-(kt-1) barrier. Only stage loads touch vmcnt in the loop.
// Swizzle (64-B rows): LDS chunk c holds global chunk c^((row>>1)&3),
// frag read at (quad^((colA>>1)&3))*16 -- r10-measured 0 conflicts.
// Epilogue (h-interleaved float4 gates, hoisted c_prev) = champion r9.
// ---------------------------------------------------------------------------

typedef __attribute__((ext_vector_type(8))) short short8;   // 8 bf16 = 4 VGPRs
typedef __attribute__((ext_vector_type(4))) float floatx4;  // MFMA acc

#define AS1(p) ((const __attribute__((address_space(1))) void*)(p))
#define AS3(p) ((__attribute__((address_space(3))) void*)(p))

__device__ __forceinline__ unsigned short f2bf(float f) {
  union { float f; unsigned u; } v; v.f = f;
  unsigned u = v.u;
  return (unsigned short)((u + 0x7fffu + ((u >> 16) & 1u)) >> 16);  // RNE
}

// --------------------------- pack everything -------------------------------
// blocks [0,8192):    A[b][k] = k<512 ? x[b][k] : h[b][k-512]     (8192x1024)
// blocks [8192,10240): B[n][k], n = hh*4 + g (h-interleaved gates f,i,g,o),
//                      k<512 -> Wx else Wh; bias[n] = bx+bh at k==0.
struct PackArgs {
  const float* x; const float* h;
  const float* wx[4]; const float* wh[4];
  const float* bx[4]; const float* bh[4];
  unsigned short* A; unsigned short* B; float* bias;
};

__global__ __launch_bounds__(256) void pack_all_kernel(PackArgs P) {
  const int bid = blockIdx.x;
  if (bid < 8192) {
    int e = (bid * 256 + threadIdx.x) * 4;
    int b = e >> 10, k = e & 1023;
    const float* src = (k < 512) ? (P.x + b * 512 + k)
                                 : (P.h + b * 512 + (k - 512));
    float4 v = *(const float4*)src;
    ushort4 o;
    o.x = f2bf(v.x); o.y = f2bf(v.y); o.z = f2bf(v.z); o.w = f2bf(v.w);
    *(ushort4*)(P.A + e) = o;
  } else {
    int e = ((bid - 8192) * 256 + threadIdx.x) * 4;
    int n = e >> 10, k = e & 1023;
    int g = n & 3, hh = n >> 2;                 // h-interleaved layout
    const float* src = (k < 512) ? (P.wx[g] + hh * 512 + k)
                                 : (P.wh[g] + hh * 512 + (k - 512));
    float4 v = *(const float4*)src;
    ushort4 o;
    o.x = f2bf(v.x); o.y = f2bf(v.y); o.z = f2bf(v.z); o.w = f2bf(v.w);
    *(ushort4*)(P.B + e) = o;
    if (k == 0) P.bias[n] = P.bx[g][hh] + P.bh[g][hh];
  }
}

// --------------------------- fused GEMM + LSTM epilogue --------------------
// Grid (32,16): tile = 256 batch x 128 cols (32 hidden x 4 gates). K=1024,
// BK=32 (32 steps). 512 threads = 8 waves; wave tile 64x64 (4x4 frags).
// LDS: buf b at b*24576: A [256 rows][64B] +0, B [128][64B] +16384.
// 3 buffers = 73728 B; epilogue ep[64][132] f32 overlays buffers.
__global__ __launch_bounds__(512, 4)
void lstm_gemm_kernel(const unsigned short* __restrict__ A,   // [8192][1024]
                      const unsigned short* __restrict__ B,   // [2048][1024]
                      const float* __restrict__ bias,         // [2048]
                      const float* __restrict__ c_prev,       // [8192][512]
                      float* __restrict__ h_out,              // [8192][512]
                      float* __restrict__ c_out) {            // [8192][512]
  __shared__ __align__(16) char smem[73728];
  __shared__ __align__(16) float biasS[128];

  const int tid  = threadIdx.x;
  const int lane = tid & 63;
  const int w    = tid >> 6;        // wave 0..7
  const int quad = lane >> 4;
  const int colA = lane & 15;
  const int m0   = blockIdx.x * 256;
  const int n0   = blockIdx.y * 128;    // = 4*h0
  const int h0   = blockIdx.y * 32;

  if (tid < 128) biasS[tid] = bias[n0 + tid];   // contiguous (h-interleave)

  const int wm = (w >> 1) * 64;     // wave M offset (0,64,128,192)
  const int wn = (w & 1) * 64;      // wave N offset (0 or 64)

  // staging: thread t covers row t>>2 (per instr), chunk t&3 of a 64-B row;
  // global source chunk = (t&3) ^ ((row>>1)&3), LDS dest linear t*16.
  const int sR   = tid >> 2;                          // 0..127
  const int cs16 = ((tid & 3) ^ ((tid >> 3) & 3)) * 16;
  // frag reads: row = wm/wn + i*16 + colA; stored chunk for global chunk
  // quad is quad ^ ((colA>>1)&3)
  const int swzF = (quad ^ ((colA >> 1) & 3)) * 16;

  const char* Ag = (const char*)A;
  const char* Bg = (const char*)B;

  floatx4 acc[4][4];
#pragma unroll
  for (int i = 0; i < 4; ++i)
#pragma unroll
    for (int j = 0; j < 4; ++j) acc[i][j] = (floatx4){0.f, 0.f, 0.f, 0.f};

  auto stage = [&](int ktt, int base) {
    const int kb = ktt * 64;              // byte offset into 2048-B rows
#pragma unroll
    for (int j = 0; j < 2; ++j)           // A: 256 rows, 2 instrs
      __builtin_amdgcn_global_load_lds(
          AS1(Ag + (size_t)(m0 + j * 128 + sR) * 2048 + kb + cs16),
          AS3(smem + base + j * 8192 + tid * 16), 16, 0, 0);
    __builtin_amdgcn_global_load_lds(     // B: 128 rows, 1 instr
        AS1(Bg + (size_t)(n0 + sR) * 2048 + kb + cs16),
        AS3(smem + base + 16384 + tid * 16), 16, 0, 0);
  };

  auto step = [&](int base) {
    short8 af[4], bfr[4];
#pragma unroll
    for (int mi = 0; mi < 4; ++mi)
      af[mi] = *(const short8*)(smem + base + (wm + mi * 16 + colA) * 64 + swzF);
#pragma unroll
    for (int ni = 0; ni < 4; ++ni)
      bfr[ni] = *(const short8*)(smem + base + 16384 + (wn + ni * 16 + colA) * 64 + swzF);
#pragma unroll
    for (int mi = 0; mi < 4; ++mi)
#pragma unroll
      for (int ni = 0; ni < 4; ++ni)
        acc[mi][ni] = __builtin_amdgcn_mfma_f32_16x16x32_bf16(
            af[mi], bfr[ni], acc[mi][ni], 0, 0, 0);
  };

  // ---- prologue: tiles 0,1 staged; wait tile 0 only (vmcnt 6->3) ----
  stage(0, 0); stage(1, 24576);
  asm volatile("s_waitcnt vmcnt(3)" ::: "memory");
  __builtin_amdgcn_s_barrier();

  int cA = 0, cB = 24576, cC = 49152;     // bufs for kt, kt+1, kt+2
  for (int kt = 0; kt < 30; ++kt) {
    stage(kt + 2, cC);                    // stays in flight across barrier
    step(cA);
    asm volatile("s_waitcnt vmcnt(3)" ::: "memory");  // stage(kt+1) landed
    __builtin_amdgcn_s_barrier();
    int t = cA; cA = cB; cB = cC; cC = t;
  }
  step(cA);                               // kt = 30
  asm volatile("s_waitcnt vmcnt(0)" ::: "memory");    // stage(31) landed
  __builtin_amdgcn_s_barrier();
  step(cB);                               // kt = 31
  asm volatile("s_waitcnt vmcnt(0)" ::: "memory");
  __builtin_amdgcn_s_barrier();           // all reads done; ep may overlay

  // ------------------- fused epilogue (4 rounds of 64 M-rows) --------------
  float* ep = (float*)smem;         // [64][132] padded, overlays buffers
#pragma unroll
  for (int rd = 0; rd < 4; ++rd) {
    // c_prev hoisted: HBM latency hides under ep writes + barrier
    float cp[4];
#pragma unroll
    for (int j = 0; j < 4; ++j) {
      int idx  = j * 512 + tid;     // 0..2047
      int mloc = idx >> 5;
      int hh   = idx & 31;
      cp[j] = c_prev[(m0 + rd * 64 + mloc) * 512 + h0 + hh];
    }
    if ((w >> 1) == rd) {           // the 2 waves with wm == rd*64
      // C/D layout: row = quad*4 + rr, col = lane&15
#pragma unroll
      for (int mi = 0; mi < 4; ++mi)
#pragma unroll
        for (int ni = 0; ni < 4; ++ni) {
          int rr0 = mi * 16 + quad * 4;                 // 0..63
          int cc  = wn + ni * 16 + colA;                // 0..127
#pragma unroll
          for (int rr = 0; rr < 4; ++rr)
            ep[(rr0 + rr) * 132 + cc] = acc[mi][ni][rr];
        }
    }
    __syncthreads();
#pragma unroll
    for (int j = 0; j < 4; ++j) {
      int idx  = j * 512 + tid;     // 0..2047
      int mloc = idx >> 5;
      int hh   = idx & 31;
      // one aligned float4 = (f,i,g,o) pre-activations for this (m,h)
      float4 pre = *(const float4*)(ep + mloc * 132 + hh * 4);
      float4 bb  = *(const float4*)(biasS + hh * 4);
      float pf = pre.x + bb.x;
      float pi = pre.y + bb.y;
      float pg = pre.z + bb.z;
      float po = pre.w + bb.w;
      float fg = 1.f / (1.f + __expf(-pf));
      float ig = 1.f / (1.f + __expf(-pi));
      float gg = 1.f - 2.f / (1.f + __expf(2.f * pg));
      float og = 1.f / (1.f + __expf(-po));
      float cv = fg * cp[j] + ig * gg;
      float th = 1.f - 2.f / (1.f + __expf(2.f * cv));
      int m  = m0 + rd * 64 + mloc;
      int hg = h0 + hh;
      h_out[m * 512 + hg] = og * th;
      c_out[m * 512 + hg] = cv;
    }
    __syncthreads();
  }
}

// ---------------------------------------------------------------------------
extern "C" void kernel_launch(void* const* d_in, const int* in_sizes, int n_in,
                              void* d_out, int out_size, void* d_ws, size_t ws_size,
                              hipStream_t stream) {
  // workspace: A_bf16 (16 MiB) | B_bf16 (4 MiB) | bias (8 KiB)
  char* ws = (char*)d_ws;
  unsigned short* Abf = (unsigned short*)ws;
  unsigned short* Bbf = (unsigned short*)(ws + (size_t)16777216);
  float* bias = (float*)(ws + (size_t)16777216 + 4194304);

  float* hout = (float*)d_out;
  float* cout = hout + (size_t)8192 * 512;

  PackArgs P;
  P.x = (const float*)d_in[0];
  P.h = (const float*)d_in[1];
  // gate order: 0=f, 1=i, 2=g(cell), 3=o
  P.wx[0] = (const float*)d_in[3];  P.bx[0] = (const float*)d_in[4];
  P.wh[0] = (const float*)d_in[5];  P.bh[0] = (const float*)d_in[6];
  P.wx[1] = (const float*)d_in[7];  P.bx[1] = (const float*)d_in[8];
  P.wh[1] = (const float*)d_in[9];  P.bh[1] = (const float*)d_in[10];
  P.wx[2] = (const float*)d_in[11]; P.bx[2] = (const float*)d_in[12];
  P.wh[2] = (const float*)d_in[13]; P.bh[2] = (const float*)d_in[14];
  P.wx[3] = (const float*)d_in[15]; P.bx[3] = (const float*)d_in[16];
  P.wh[3] = (const float*)d_in[17]; P.bh[3] = (const float*)d_in[18];
  P.A = Abf; P.B = Bbf; P.bias = bias;

  pack_all_kernel<<<10240, 256, 0, stream>>>(P);

  const float* c = (const float*)d_in[2];
  dim3 grid(32, 16);
  lstm_gemm_kernel<<<grid, 512, 0, stream>>>(Abf, Bbf, bias, c, hout, cout);
}

// Round 9
// 164.779 us; speedup vs baseline: 1.0454x; 1.0454x over previous
//
#include <hip/hip_runtime.h>
#include <cstdint>
#include <cstddef>

// ---------------------------------------------------------------------------
// LSTM cell, B=8192, D=H=512, fp32 in/out.
// pre = [x|h] @ Wstack^T + bias ; gates -> c_t, h_t fused in GEMM epilogue.
// Round 12: champion r9 GEMM untouched (45.9us; six structural variants all
// regressed: 8-phase x2, 4blk/CU, fp32-direct, reg-direct, dbuf-drain,
// counted-vmcnt). This round optimizes the PACK only: 8 elems/thread
// (2x float4 read, 1x short8 16B write, G13 width sweet spot), 5120 blocks
// instead of 10240 -> half the instruction/launch overhead on a pure
// streaming kernel. Chunk of 8 never straddles the k=512 x/h boundary.
// ---------------------------------------------------------------------------

typedef __attribute__((ext_vector_type(8))) short short8;   // 8 bf16 = 4 VGPRs
typedef __attribute__((ext_vector_type(4))) float floatx4;  // MFMA acc

#define AS1(p) ((const __attribute__((address_space(1))) void*)(p))
#define AS3(p) ((__attribute__((address_space(3))) void*)(p))

__device__ __forceinline__ unsigned short f2bf(float f) {
  union { float f; unsigned u; } v; v.f = f;
  unsigned u = v.u;
  return (unsigned short)((u + 0x7fffu + ((u >> 16) & 1u)) >> 16);  // RNE
}

// --------------------------- pack everything -------------------------------
// A[b][k] = k<512 ? x[b][k] : h[b][k-512]                  (8192x1024 bf16)
// B[n][k], n = hh*4 + g (h-interleaved gates f,i,g,o), k<512 -> Wx else Wh;
// bias[n] = bx+bh written by the k==0 thread.
// v2: 8 elems per thread. A: gid in [0, 1048576) -> row gid>>7, chunk gid&127.
//     B: gid' = gid-1048576 in [0, 262144) -> n = gid'>>7, chunk gid'&127.
struct PackArgs {
  const float* x; const float* h;
  const float* wx[4]; const float* wh[4];
  const float* bx[4]; const float* bh[4];
  unsigned short* A; unsigned short* B; float* bias;
};

__global__ __launch_bounds__(256) void pack_all_kernel(PackArgs P) {
  const int gid = blockIdx.x * 256 + threadIdx.x;
  const float* src;
  unsigned short* dst;
  if (gid < 1048576) {                    // ---- A: 8192 rows x 128 chunks ----
    int b = gid >> 7, k = (gid & 127) * 8;
    src = (k < 512) ? (P.x + b * 512 + k) : (P.h + b * 512 + (k - 512));
    dst = P.A + ((size_t)b << 10) + k;
  } else {                                // ---- B: 2048 rows x 128 chunks ----
    int g2 = gid - 1048576;
    int n = g2 >> 7, k = (g2 & 127) * 8;
    int g = n & 3, hh = n >> 2;           // h-interleaved layout
    src = (k < 512) ? (P.wx[g] + hh * 512 + k) : (P.wh[g] + hh * 512 + (k - 512));
    dst = P.B + ((size_t)n << 10) + k;
    if (k == 0) P.bias[n] = P.bx[g][hh] + P.bh[g][hh];
  }
  float4 v0 = ((const float4*)src)[0];
  float4 v1 = ((const float4*)src)[1];
  union { unsigned short us[8]; short8 s; } o;
  o.us[0] = f2bf(v0.x); o.us[1] = f2bf(v0.y);
  o.us[2] = f2bf(v0.z); o.us[3] = f2bf(v0.w);
  o.us[4] = f2bf(v1.x); o.us[5] = f2bf(v1.y);
  o.us[6] = f2bf(v1.z); o.us[7] = f2bf(v1.w);
  *(short8*)dst = o.s;
}

// --------------------------- fused GEMM + LSTM epilogue --------------------
// Grid (32,16): tile = 256 batch x 128 cols (32 hidden x 4 gates). K=1024,
// BK=64. 512 threads = 8 waves; wave tile 64x64 (4x4 frags of 16x16x32).
// LDS: As 32KB @ [0,32768), Bs 16KB @ [32768,49152); epilogue overlays As.
// (byte-identical to the round-9 champion: 45.9us, MfmaUtil 29, 0 conflicts)
__global__ __launch_bounds__(512, 4)
void lstm_gemm_kernel(const unsigned short* __restrict__ A,   // [8192][1024]
                      const unsigned short* __restrict__ B,   // [2048][1024]
                      const float* __restrict__ bias,         // [2048]
                      const float* __restrict__ c_prev,       // [8192][512]
                      float* __restrict__ h_out,              // [8192][512]
                      float* __restrict__ c_out) {            // [8192][512]
  __shared__ __align__(16) char smem[49152];
  __shared__ __align__(16) float biasS[128];

  const int tid  = threadIdx.x;
  const int lane = tid & 63;
  const int w    = tid >> 6;        // wave 0..7
  const int quad = lane >> 4;
  const int colA = lane & 15;
  const int m0   = blockIdx.x * 256;
  const int n0   = blockIdx.y * 128;    // = 4*h0
  const int h0   = blockIdx.y * 32;

  if (tid < 128) biasS[tid] = bias[n0 + tid];   // contiguous (h-interleave)

  // staging: thread covers tile-row r = j*64 + (tid>>3), 16B chunk (tid&7);
  // global chunk XOR-swizzled by row&7 so ds_read_b128 frags are conflict-free
  const int srow = tid >> 3;        // 0..63
  const int cl   = tid & 7;
  const int cg   = cl ^ (srow & 7);

  floatx4 acc[4][4];
#pragma unroll
  for (int i = 0; i < 4; ++i)
#pragma unroll
    for (int j = 0; j < 4; ++j) acc[i][j] = (floatx4){0.f, 0.f, 0.f, 0.f};

  const int wm = (w >> 1) * 64;     // wave M offset in tile (0,64,128,192)
  const int wn = (w & 1) * 64;      // wave N offset (0 or 64)

  const char* Ag = (const char*)A;
  const char* Bg = (const char*)B;

  for (int kt = 0; kt < 16; ++kt) {
    __syncthreads();                // prior LDS reads done
    const int kb = kt * 128;        // byte offset into 2048-B rows
#pragma unroll
    for (int j = 0; j < 4; ++j) {   // A: 256 rows
      int r = j * 64 + srow;        // tile row 0..255 (r&7 == srow&7)
      __builtin_amdgcn_global_load_lds(
          AS1(Ag + (size_t)(m0 + r) * 2048 + kb + cg * 16),
          AS3(smem + r * 128 + cl * 16), 16, 0, 0);
    }
#pragma unroll
    for (int j = 0; j < 2; ++j) {   // B: 128 rows (h-interleaved)
      int r = j * 64 + srow;        // tile row 0..127
      __builtin_amdgcn_global_load_lds(
          AS1(Bg + (size_t)(n0 + r) * 2048 + kb + cg * 16),
          AS3(smem + 32768 + r * 128 + cl * 16), 16, 0, 0);
    }
    __syncthreads();                // drains vmcnt(0)

#pragma unroll
    for (int kk = 0; kk < 2; ++kk) {
      const int off = ((kk * 4 + quad) ^ (colA & 7)) * 16;
      short8 af[4], bfr[4];
#pragma unroll
      for (int mi = 0; mi < 4; ++mi)
        af[mi] = *(const short8*)(smem + (wm + mi * 16 + colA) * 128 + off);
#pragma unroll
      for (int ni = 0; ni < 4; ++ni)
        bfr[ni] = *(const short8*)(smem + 32768 + (wn + ni * 16 + colA) * 128 + off);
#pragma unroll
      for (int mi = 0; mi < 4; ++mi)
#pragma unroll
        for (int ni = 0; ni < 4; ++ni)
          acc[mi][ni] = __builtin_amdgcn_mfma_f32_16x16x32_bf16(
              af[mi], bfr[ni], acc[mi][ni], 0, 0, 0);
    }
  }

  // ------------------- fused epilogue (4 rounds of 64 M-rows) --------------
  __syncthreads();
  float* ep = (float*)smem;         // [64][132] padded, overlays As
#pragma unroll
  for (int rd = 0; rd < 4; ++rd) {
    // c_prev hoisted: HBM latency hides under ep writes + barrier
    float cp[4];
#pragma unroll
    for (int j = 0; j < 4; ++j) {
      int idx  = j * 512 + tid;     // 0..2047
      int mloc = idx >> 5;
      int hh   = idx & 31;
      cp[j] = c_prev[(m0 + rd * 64 + mloc) * 512 + h0 + hh];
    }
    if ((w >> 1) == rd) {           // the 2 waves with wm == rd*64
      // C/D layout: row = quad*4 + rr, col = lane&15
#pragma unroll
      for (int mi = 0; mi < 4; ++mi)
#pragma unroll
        for (int ni = 0; ni < 4; ++ni) {
          int rr0 = mi * 16 + quad * 4;                 // 0..63
          int cc  = wn + ni * 16 + colA;                // 0..127
#pragma unroll
          for (int rr = 0; rr < 4; ++rr)
            ep[(rr0 + rr) * 132 + cc] = acc[mi][ni][rr];
        }
    }
    __syncthreads();
#pragma unroll
    for (int j = 0; j < 4; ++j) {
      int idx  = j * 512 + tid;     // 0..2047
      int mloc = idx >> 5;
      int hh   = idx & 31;
      // one aligned float4 = (f,i,g,o) pre-activations for this (m,h)
      float4 pre = *(const float4*)(ep + mloc * 132 + hh * 4);
      float4 bb  = *(const float4*)(biasS + hh * 4);
      float pf = pre.x + bb.x;
      float pi = pre.y + bb.y;
      float pg = pre.z + bb.z;
      float po = pre.w + bb.w;
      float fg = 1.f / (1.f + __expf(-pf));
      float ig = 1.f / (1.f + __expf(-pi));
      float gg = 1.f - 2.f / (1.f + __expf(2.f * pg));
      float og = 1.f / (1.f + __expf(-po));
      float cv = fg * cp[j] + ig * gg;
      float th = 1.f - 2.f / (1.f + __expf(2.f * cv));
      int m  = m0 + rd * 64 + mloc;
      int hg = h0 + hh;
      h_out[m * 512 + hg] = og * th;
      c_out[m * 512 + hg] = cv;
    }
    __syncthreads();
  }
}

// ---------------------------------------------------------------------------
extern "C" void kernel_launch(void* const* d_in, const int* in_sizes, int n_in,
                              void* d_out, int out_size, void* d_ws, size_t ws_size,
                              hipStream_t stream) {
  // workspace: A_bf16 (16 MiB) | B_bf16 (4 MiB) | bias (8 KiB)
  char* ws = (char*)d_ws;
  unsigned short* Abf = (unsigned short*)ws;
  unsigned short* Bbf = (unsigned short*)(ws + (size_t)16777216);
  float* bias = (float*)(ws + (size_t)16777216 + 4194304);

  float* hout = (float*)d_out;
  float* cout = hout + (size_t)8192 * 512;

  PackArgs P;
  P.x = (const float*)d_in[0];
  P.h = (const float*)d_in[1];
  // gate order: 0=f, 1=i, 2=g(cell), 3=o
  P.wx[0] = (const float*)d_in[3];  P.bx[0] = (const float*)d_in[4];
  P.wh[0] = (const float*)d_in[5];  P.bh[0] = (const float*)d_in[6];
  P.wx[1] = (const float*)d_in[7];  P.bx[1] = (const float*)d_in[8];
  P.wh[1] = (const float*)d_in[9];  P.bh[1] = (const float*)d_in[10];
  P.wx[2] = (const float*)d_in[11]; P.bx[2] = (const float*)d_in[12];
  P.wh[2] = (const float*)d_in[13]; P.bh[2] = (const float*)d_in[14];
  P.wx[3] = (const float*)d_in[15]; P.bx[3] = (const float*)d_in[16];
  P.wh[3] = (const float*)d_in[17]; P.bh[3] = (const float*)d_in[18];
  P.A = Abf; P.B = Bbf; P.bias = bias;

  // A: 1048576 threads + B: 262144 threads = 5120 blocks of 256
  pack_all_kernel<<<5120, 256, 0, stream>>>(P);

  const float* c = (const float*)d_in[2];
  dim3 grid(32, 16);
  lstm_gemm_kernel<<<grid, 512, 0, stream>>>(Abf, Bbf, bias, c, hout, cout);
}